// Round 3
// baseline (380.255 us; speedup 1.0000x reference)
//
#include <hip/hip_runtime.h>
#include <hip/hip_bf16.h>
#include <math.h>

#define NTOK 4096
#define DIMSZ 1024
#define HID 4096
#define NE 8
#define RT_MAX 40   // max sum over experts of ceil(count/128) is 39; pad to 40

typedef unsigned short u16;
typedef unsigned int u32;
typedef __attribute__((ext_vector_type(8))) short bf16x8;
typedef __attribute__((ext_vector_type(4))) float f32x4;

static __device__ __forceinline__ u16 f2bf(float f) {
    u32 u = __float_as_uint(f);
    u32 r = u + 0x7fffu + ((u >> 16) & 1u);   // round-to-nearest-even
    return (u16)(r >> 16);
}

static __device__ __forceinline__ u32 pk2bf(float lo, float hi) {
    __hip_bfloat162 h = __float22bfloat162_rn(make_float2(lo, hi));
    return *(u32*)&h;
}

// ---------------- init: zero counts + cursor ----------------
__global__ void k_init(int* counts, int* cursor) {
    if (threadIdx.x < NE) { counts[threadIdx.x] = 0; cursor[threadIdx.x] = 0; }
}

// ---------------- router: fp32 argmax over 8 experts ----------------
__global__ __launch_bounds__(256) void k_router(const float* __restrict__ x,
                                                const float* __restrict__ Wg,
                                                int* __restrict__ ids,
                                                int* __restrict__ counts) {
    int wave = threadIdx.x >> 6;
    int lane = threadIdx.x & 63;
    int t = blockIdx.x * 4 + wave;

    const float4* xr = (const float4*)(x + (size_t)t * DIMSZ);
    float4 xv[4];
#pragma unroll
    for (int j = 0; j < 4; j++) xv[j] = xr[j * 64 + lane];

    float s[NE];
#pragma unroll
    for (int e = 0; e < NE; e++) {
        const float4* wr = (const float4*)(Wg + (size_t)e * DIMSZ);
        float p = 0.f;
#pragma unroll
        for (int j = 0; j < 4; j++) {
            float4 w = wr[j * 64 + lane];
            p += xv[j].x * w.x + xv[j].y * w.y + xv[j].z * w.z + xv[j].w * w.w;
        }
#pragma unroll
        for (int m = 32; m >= 1; m >>= 1) p += __shfl_xor(p, m, 64);
        s[e] = p;
    }
    if (lane == 0) {
        int best = 0;
#pragma unroll
        for (int e = 1; e < NE; e++) if (s[e] > s[best]) best = e;  // first-max tiebreak
        ids[t] = best;
        atomicAdd(&counts[best], 1);
    }
}

// ---------------- scan: exclusive prefix over 8 counts ----------------
__global__ void k_scan(const int* __restrict__ counts, int* __restrict__ offs) {
    if (threadIdx.x == 0) {
        int a = 0;
        for (int e = 0; e < NE; e++) { offs[e] = a; a += counts[e]; }
    }
}

// ---------------- gather: build perm + bf16-convert x into grouped Xg ----------------
__global__ __launch_bounds__(256) void k_gather(const float* __restrict__ x,
                                                const int* __restrict__ ids,
                                                const int* __restrict__ offs,
                                                int* __restrict__ cursor,
                                                int* __restrict__ perm,
                                                u16* __restrict__ Xg) {
    int t = blockIdx.x;
    __shared__ int sp;
    if (threadIdx.x == 0) {
        int e = ids[t];
        int p = offs[e] + atomicAdd(&cursor[e], 1);
        perm[p] = t;
        sp = p;
    }
    __syncthreads();
    int p = sp;
    const float4* src = (const float4*)(x + (size_t)t * DIMSZ);
    float4 v = src[threadIdx.x];
    u32 w0 = pk2bf(v.x, v.y);
    u32 w1 = pk2bf(v.z, v.w);
    uint2* dst = (uint2*)(Xg + (size_t)p * DIMSZ + threadIdx.x * 4);
    *dst = make_uint2(w0, w1);
}

// ---------------- grouped GEMM: 128x128 tile, BK=64, 4 waves, 2-phase dbuf ----------------
// A: grouped bf16 rows [NTOK][KDIM]; staged via global_load_lds (linear LDS dest,
//    inverse-swizzled GLOBAL source — rule #21).
// Ball: fp32 [NE][KDIM][NDIM]; reg-staged: float4 loads (next iter) issued at top,
//    cvt_pk + swizzled ds_write_b128 at bottom (T14 issue-early/write-late).
// LDS: double-buffered [2][128][64] u16, XOR swizzle byte ^= ((row&7)<<4).
// One __syncthreads per K-step (drains vmcnt for A + lgkm for B writes).
// EPI==1: H[p*NDIM+col] = bf16(gelu(acc+b1))   EPI==2: out[perm[p]*NDIM+col] = acc+b2
template <int KDIM, int NDIM, int EPI>
__global__ __launch_bounds__(256) void k_gemm(const u16* __restrict__ A,
                                              const float* __restrict__ Ball,
                                              const float* __restrict__ biasAll,
                                              const int* __restrict__ counts,
                                              const int* __restrict__ offs,
                                              const int* __restrict__ perm,
                                              u16* __restrict__ Hout,
                                              float* __restrict__ Fout) {
    constexpr int NT = NDIM / 128;
    constexpr int NWG = RT_MAX * NT;   // multiple of 8 for both instantiations
    constexpr int CPX = NWG / 8;
    constexpr int NK = KDIM / 64;
    int bid = blockIdx.x;
    int wid = (bid & 7) * CPX + (bid >> 3);   // bijective XCD swizzle
    int x = wid % RT_MAX;                      // row-tile (fast axis -> same XCD)
    int n0 = (wid / RT_MAX) * 128;             // n-stripe

    // map x -> (expert, local row tile)
    int e = -1, lrt = 0, a0 = 0;
#pragma unroll
    for (int i = 0; i < NE; i++) {
        int rt = (counts[i] + 127) >> 7;
        if (e < 0 && x < a0 + rt) { e = i; lrt = x - a0; }
        a0 += rt;
    }
    if (e < 0) return;
    int row0 = offs[e] + lrt * 128;
    int nrows = offs[e] + counts[e] - row0;
    if (nrows > 128) nrows = 128;

    __shared__ alignas(16) u16 As[2][128][64];   // [buf][row][k], 128B rows, swizzled
    __shared__ alignas(16) u16 Bs[2][128][64];   // [buf][n][k],   128B rows, swizzled

    int tid = threadIdx.x;
    int lane = tid & 63;
    int wave = tid >> 6;
    int wr = wave >> 1, wc = wave & 1;

    // --- A staging: granule g = p*256+tid -> LDS row r=g>>3, slot g&7; source k-block
    // pre-swizzled: slot s reads k-block s^(r&7).
    const u16* srcA[4];
#pragma unroll
    for (int p = 0; p < 4; p++) {
        int g = p * 256 + tid;
        int r = g >> 3, slot = g & 7;
        int rc = r < nrows ? r : nrows - 1;
        srcA[p] = A + (size_t)(row0 + rc) * KDIM + ((slot ^ (r & 7)) * 8);
    }
    // --- B staging: thread loads 8 k-rows x 4 consecutive n (dwordx4)
    int bn4 = (tid & 31) * 4;   // base n
    int bkb = tid >> 5;         // k-block 0..7 (8 consecutive k)
    const float* srcB = Ball + (size_t)e * KDIM * NDIM + (size_t)(bkb * 8) * NDIM + n0 + bn4;

    f32x4 acc[4][4] = {};
    int fr = lane & 15, fc = lane >> 4;

    float4 breg[8];

#define LOAD_B(KK)                                                              \
    {                                                                           \
        const float* bp = srcB + (size_t)(KK) * 64 * NDIM;                      \
        _Pragma("unroll")                                                       \
        for (int j = 0; j < 8; j++) breg[j] = *(const float4*)(bp + (size_t)j * NDIM); \
    }

#define STAGE_A(BUF, KK)                                                        \
    {                                                                           \
        _Pragma("unroll")                                                       \
        for (int p = 0; p < 4; p++) {                                           \
            __builtin_amdgcn_global_load_lds(                                   \
                (const __attribute__((address_space(1))) void*)(srcA[p] + (KK) * 64), \
                (__attribute__((address_space(3))) void*)((u16*)&As[BUF][0][0] + (p * 256 + wave * 64) * 8), \
                16, 0, 0);                                                      \
        }                                                                       \
    }

#define WRITE_B(BUF)                                                            \
    {                                                                           \
        const float* vf = (const float*)breg;                                   \
        _Pragma("unroll")                                                       \
        for (int i = 0; i < 4; i++) {                                           \
            int N = bn4 + i;                                                    \
            u32 w0 = pk2bf(vf[0 + i],  vf[4 + i]);                              \
            u32 w1 = pk2bf(vf[8 + i],  vf[12 + i]);                             \
            u32 w2 = pk2bf(vf[16 + i], vf[20 + i]);                             \
            u32 w3 = pk2bf(vf[24 + i], vf[28 + i]);                             \
            u32 off = (u32)(bkb * 16) ^ (u32)((N & 7) << 4);                    \
            *(uint4*)((char*)&Bs[BUF][N][0] + off) = make_uint4(w0, w1, w2, w3); \
        }                                                                       \
    }

    // prologue: fill buffer 0
    LOAD_B(0);
    STAGE_A(0, 0);
    WRITE_B(0);
    __syncthreads();

    for (int kk = 0; kk < NK; kk++) {
        int cur = kk & 1;
        // issue next-tile loads first (fly during compute)
        if (kk + 1 < NK) {
            LOAD_B(kk + 1);
            STAGE_A(cur ^ 1, kk + 1);
        }
        // compute current buffer
#pragma unroll
        for (int k2 = 0; k2 < 2; k2++) {
            bf16x8 af[4], bfr[4];
#pragma unroll
            for (int m = 0; m < 4; m++) {
                int r = wr * 64 + m * 16 + fr;
                u32 off = (u32)(k2 * 64 + fc * 16) ^ (u32)((r & 7) << 4);
                af[m] = *(const bf16x8*)((const char*)&As[cur][r][0] + off);
            }
#pragma unroll
            for (int n = 0; n < 4; n++) {
                int N = wc * 64 + n * 16 + fr;
                u32 off = (u32)(k2 * 64 + fc * 16) ^ (u32)((N & 7) << 4);
                bfr[n] = *(const bf16x8*)((const char*)&Bs[cur][N][0] + off);
            }
#pragma unroll
            for (int m = 0; m < 4; m++)
#pragma unroll
                for (int n = 0; n < 4; n++)
                    acc[m][n] = __builtin_amdgcn_mfma_f32_16x16x32_bf16(af[m], bfr[n], acc[m][n], 0, 0, 0);
        }
        // write next B tile (after compute; its loads have had the MFMA section to land)
        if (kk + 1 < NK) {
            WRITE_B(cur ^ 1);
            __syncthreads();   // drains A global_load_lds (vmcnt) + B ds_writes (lgkm)
        }
    }
#undef LOAD_B
#undef STAGE_A
#undef WRITE_B

    // epilogue (C/D layout: col = lane&15, row = (lane>>4)*4 + j)
    int cb = lane & 15;
    int rq = lane >> 4;
#pragma unroll
    for (int m = 0; m < 4; m++) {
        int rbase = wr * 64 + m * 16 + rq * 4;
#pragma unroll
        for (int n = 0; n < 4; n++) {
            int col = n0 + wc * 64 + n * 16 + cb;
            float bias = biasAll[(size_t)e * NDIM + col];
#pragma unroll
            for (int j = 0; j < 4; j++) {
                int r = rbase + j;
                if (r < nrows) {
                    float v = acc[m][n][j] + bias;
                    int p = row0 + r;
                    if (EPI == 1) {
                        float g = 0.5f * v * (1.0f + erff(v * 0.70710678118654752f));
                        Hout[(size_t)p * NDIM + col] = f2bf(g);
                    } else {
                        int trow = perm[p];
                        Fout[(size_t)trow * NDIM + col] = v;
                    }
                }
            }
        }
    }
}

extern "C" void kernel_launch(void* const* d_in, const int* in_sizes, int n_in,
                              void* d_out, int out_size, void* d_ws, size_t ws_size,
                              hipStream_t stream) {
    const float* x  = (const float*)d_in[0];
    const float* Wg = (const float*)d_in[1];
    const float* W1 = (const float*)d_in[2];
    const float* b1 = (const float*)d_in[3];
    const float* W2 = (const float*)d_in[4];
    const float* b2 = (const float*)d_in[5];
    float* out = (float*)d_out;

    char* ws = (char*)d_ws;
    int* ids    = (int*)(ws + 0);          // 16384 B
    int* counts = (int*)(ws + 16384);      // 32 B
    int* offs   = (int*)(ws + 16448);      // 32 B
    int* cursor = (int*)(ws + 16512);      // 32 B
    int* perm   = (int*)(ws + 16576);      // 16384 B
    u16* Xg     = (u16*)(ws + 33024);      // 8 MiB   (4096x1024 bf16)
    u16* H      = (u16*)(ws + 33024 + 8388608);  // 32 MiB (4096x4096 bf16)

    k_init<<<dim3(1), dim3(64), 0, stream>>>(counts, cursor);
    k_router<<<dim3(NTOK / 4), dim3(256), 0, stream>>>(x, Wg, ids, counts);
    k_scan<<<dim3(1), dim3(64), 0, stream>>>(counts, offs);
    k_gather<<<dim3(NTOK), dim3(256), 0, stream>>>(x, ids, offs, cursor, perm, Xg);
    k_gemm<DIMSZ, HID, 1><<<dim3(RT_MAX * (HID / 128)), dim3(256), 0, stream>>>(
        Xg, W1, b1, counts, offs, perm, H, (float*)nullptr);
    k_gemm<HID, DIMSZ, 2><<<dim3(RT_MAX * (DIMSZ / 128)), dim3(256), 0, stream>>>(
        H, W2, b2, counts, offs, perm, (u16*)nullptr, out);
}

// Round 4
// 310.301 us; speedup vs baseline: 1.2254x; 1.2254x over previous
//
#include <hip/hip_runtime.h>
#include <hip/hip_bf16.h>
#include <math.h>

#define NTOK 4096
#define DIMSZ 1024
#define HID 4096
#define NE 8
#define RT_MAX 40   // max sum over experts of ceil(count/128) is 39; pad to 40

typedef unsigned short u16;
typedef unsigned int u32;
typedef __attribute__((ext_vector_type(8))) short bf16x8;
typedef __attribute__((ext_vector_type(4))) float f32x4;

static __device__ __forceinline__ u16 f2bf(float f) {
    u32 u = __float_as_uint(f);
    u32 r = u + 0x7fffu + ((u >> 16) & 1u);   // round-to-nearest-even
    return (u16)(r >> 16);
}

static __device__ __forceinline__ u32 pk2bf(float lo, float hi) {
    __hip_bfloat162 h = __float22bfloat162_rn(make_float2(lo, hi));
    return *(u32*)&h;
}

// ---------------- init: zero counts + cursor ----------------
__global__ void k_init(int* counts, int* cursor) {
    if (threadIdx.x < NE) { counts[threadIdx.x] = 0; cursor[threadIdx.x] = 0; }
}

// ---------------- router: fp32 argmax over 8 experts ----------------
__global__ __launch_bounds__(256) void k_router(const float* __restrict__ x,
                                                const float* __restrict__ Wg,
                                                int* __restrict__ ids,
                                                int* __restrict__ counts) {
    int wave = threadIdx.x >> 6;
    int lane = threadIdx.x & 63;
    int t = blockIdx.x * 4 + wave;

    const float4* xr = (const float4*)(x + (size_t)t * DIMSZ);
    float4 xv[4];
#pragma unroll
    for (int j = 0; j < 4; j++) xv[j] = xr[j * 64 + lane];

    float s[NE];
#pragma unroll
    for (int e = 0; e < NE; e++) {
        const float4* wr = (const float4*)(Wg + (size_t)e * DIMSZ);
        float p = 0.f;
#pragma unroll
        for (int j = 0; j < 4; j++) {
            float4 w = wr[j * 64 + lane];
            p += xv[j].x * w.x + xv[j].y * w.y + xv[j].z * w.z + xv[j].w * w.w;
        }
#pragma unroll
        for (int m = 32; m >= 1; m >>= 1) p += __shfl_xor(p, m, 64);
        s[e] = p;
    }
    if (lane == 0) {
        int best = 0;
#pragma unroll
        for (int e = 1; e < NE; e++) if (s[e] > s[best]) best = e;  // first-max tiebreak
        ids[t] = best;
        atomicAdd(&counts[best], 1);
    }
}

// ---------------- scan: exclusive prefix over 8 counts ----------------
__global__ void k_scan(const int* __restrict__ counts, int* __restrict__ offs) {
    if (threadIdx.x == 0) {
        int a = 0;
        for (int e = 0; e < NE; e++) { offs[e] = a; a += counts[e]; }
    }
}

// ---------------- gather: build perm + bf16-convert x into grouped Xg ----------------
__global__ __launch_bounds__(256) void k_gather(const float* __restrict__ x,
                                                const int* __restrict__ ids,
                                                const int* __restrict__ offs,
                                                int* __restrict__ cursor,
                                                int* __restrict__ perm,
                                                u16* __restrict__ Xg) {
    int t = blockIdx.x;
    __shared__ int sp;
    if (threadIdx.x == 0) {
        int e = ids[t];
        int p = offs[e] + atomicAdd(&cursor[e], 1);
        perm[p] = t;
        sp = p;
    }
    __syncthreads();
    int p = sp;
    const float4* src = (const float4*)(x + (size_t)t * DIMSZ);
    float4 v = src[threadIdx.x];
    u32 w0 = pk2bf(v.x, v.y);
    u32 w1 = pk2bf(v.z, v.w);
    uint2* dst = (uint2*)(Xg + (size_t)p * DIMSZ + threadIdx.x * 4);
    *dst = make_uint2(w0, w1);
}

// ---------------- grouped GEMM: 128x128 tile, BK=64, 4 waves ----------------
// Counted-vmcnt pipeline (T4): A prefetch distance 2 (triple-buffered LDS via
// global_load_lds), B prefetch distance 2 in registers (loaded iter kk, consumed
// iter kk+1), raw s_barrier, NEVER vmcnt(0) in the main loop.
// Per-iter VMEM FIFO (issue B x8 then A x4 each iter):
//   at loop head: [B(kk+1) x8 (oldest), A(kk+1) x4]
//   compute(cur) ; vmcnt(4) -> B(kk+1) landed ; cvt+ds_write Bs[nxt] ;
//   issue B(kk+2) x8, A(kk+2) x4 ; vmcnt(12) -> A(kk+1) landed ;
//   lgkmcnt(0) ; s_barrier ; rotate buffers.
// LDS 80KB -> 2 blocks/CU. Swizzles identical to verified R2/R3 kernel.
template <int KDIM, int NDIM, int EPI>
__global__ __launch_bounds__(256) void k_gemm(const u16* __restrict__ A,
                                              const float* __restrict__ Ball,
                                              const float* __restrict__ biasAll,
                                              const int* __restrict__ counts,
                                              const int* __restrict__ offs,
                                              const int* __restrict__ perm,
                                              u16* __restrict__ Hout,
                                              float* __restrict__ Fout) {
    constexpr int NT = NDIM / 128;
    constexpr int NWG = RT_MAX * NT;   // multiple of 8 for both instantiations
    constexpr int CPX = NWG / 8;
    constexpr int NK = KDIM / 64;      // 16 (GEMM1) / 64 (GEMM2)
    int bid = blockIdx.x;
    int wid = (bid & 7) * CPX + (bid >> 3);   // bijective XCD swizzle
    int x = wid % RT_MAX;                      // row-tile (fast axis -> same XCD)
    int n0 = (wid / RT_MAX) * 128;             // n-stripe

    // map x -> (expert, local row tile)
    int e = -1, lrt = 0, a0 = 0;
#pragma unroll
    for (int i = 0; i < NE; i++) {
        int rt = (counts[i] + 127) >> 7;
        if (e < 0 && x < a0 + rt) { e = i; lrt = x - a0; }
        a0 += rt;
    }
    if (e < 0) return;
    int row0 = offs[e] + lrt * 128;
    int nrows = offs[e] + counts[e] - row0;
    if (nrows > 128) nrows = 128;

    __shared__ alignas(16) u16 Asb[3][128][64];   // 48KB, rotating triple buffer
    __shared__ alignas(16) u16 Bsb[2][128][64];   // 32KB, double buffer

    int tid = threadIdx.x;
    int lane = tid & 63;
    int wave = tid >> 6;
    int wr = wave >> 1, wc = wave & 1;

    // --- A staging: granule g = p*256+tid -> LDS row r=g>>3, slot g&7; source
    // k-block pre-swizzled: slot s reads k-block s^(r&7). (rule #21)
    const u16* srcA[4];
#pragma unroll
    for (int p = 0; p < 4; p++) {
        int g = p * 256 + tid;
        int r = g >> 3, slot = g & 7;
        int rc = r < nrows ? r : nrows - 1;
        srcA[p] = A + (size_t)(row0 + rc) * KDIM + ((slot ^ (r & 7)) * 8);
    }
    // --- B staging: thread loads 8 k-rows x 4 consecutive n (dwordx4)
    int bn4 = (tid & 31) * 4;   // base n
    int bkb = tid >> 5;         // k-block 0..7 (8 consecutive k)
    const float* srcB = Ball + (size_t)e * KDIM * NDIM + (size_t)(bkb * 8) * NDIM + n0 + bn4;

    f32x4 acc[4][4] = {};
    int fr = lane & 15, fc = lane >> 4;

    float4 breg[8];
    u16 *Ar = &Asb[0][0][0], *An = &Asb[1][0][0], *Aw = &Asb[2][0][0];
    u16 *Br = &Bsb[0][0][0], *Bw = &Bsb[1][0][0];

#define LOAD_B(KT)                                                              \
    {                                                                           \
        const float* bp = srcB + (size_t)(KT) * 64 * NDIM;                      \
        _Pragma("unroll")                                                       \
        for (int j = 0; j < 8; j++) breg[j] = *(const float4*)(bp + (size_t)j * NDIM); \
    }

#define STAGE_A(DST, KT)                                                        \
    {                                                                           \
        _Pragma("unroll")                                                       \
        for (int p = 0; p < 4; p++) {                                           \
            __builtin_amdgcn_global_load_lds(                                   \
                (const __attribute__((address_space(1))) void*)(srcA[p] + (KT) * 64), \
                (__attribute__((address_space(3))) void*)((DST) + (p * 256 + wave * 64) * 8), \
                16, 0, 0);                                                      \
        }                                                                       \
    }

#define WRITE_B(DST)                                                            \
    {                                                                           \
        const float* vf = (const float*)breg;                                   \
        _Pragma("unroll")                                                       \
        for (int i = 0; i < 4; i++) {                                           \
            int N = bn4 + i;                                                    \
            u32 w0 = pk2bf(vf[0 + i],  vf[4 + i]);                              \
            u32 w1 = pk2bf(vf[8 + i],  vf[12 + i]);                             \
            u32 w2 = pk2bf(vf[16 + i], vf[20 + i]);                             \
            u32 w3 = pk2bf(vf[24 + i], vf[28 + i]);                             \
            u32 off = (u32)(bkb * 16) ^ (u32)((N & 7) << 4);                    \
            *(uint4*)((char*)(DST) + N * 128 + off) = make_uint4(w0, w1, w2, w3); \
        }                                                                       \
    }

#define COMPUTE()                                                               \
    {                                                                           \
        _Pragma("unroll")                                                       \
        for (int k2 = 0; k2 < 2; k2++) {                                        \
            bf16x8 af[4], bfr[4];                                               \
            _Pragma("unroll")                                                   \
            for (int m = 0; m < 4; m++) {                                       \
                int r = wr * 64 + m * 16 + fr;                                  \
                u32 off = (u32)(k2 * 64 + fc * 16) ^ (u32)((r & 7) << 4);       \
                af[m] = *(const bf16x8*)((const char*)Ar + r * 128 + off);      \
            }                                                                   \
            _Pragma("unroll")                                                   \
            for (int n = 0; n < 4; n++) {                                       \
                int N = wc * 64 + n * 16 + fr;                                  \
                u32 off = (u32)(k2 * 64 + fc * 16) ^ (u32)((N & 7) << 4);       \
                bfr[n] = *(const bf16x8*)((const char*)Br + N * 128 + off);     \
            }                                                                   \
            _Pragma("unroll")                                                   \
            for (int m = 0; m < 4; m++)                                         \
                _Pragma("unroll")                                               \
                for (int n = 0; n < 4; n++)                                     \
                    acc[m][n] = __builtin_amdgcn_mfma_f32_16x16x32_bf16(af[m], bfr[n], acc[m][n], 0, 0, 0); \
        }                                                                       \
    }

#define WAITV(N) asm volatile("s_waitcnt vmcnt(" #N ")" ::: "memory")
#define WAITL()  asm volatile("s_waitcnt lgkmcnt(0)" ::: "memory")
#define BAR()    __builtin_amdgcn_s_barrier()

    // ---- prologue: fill tile 0, prefetch tile 1 ----
    LOAD_B(0);                 // vmcnt: B0 x8
    STAGE_A(Ar, 0);            // + A0 x4
    WAITV(4);                  // B0 landed (A0 still in flight)
    WRITE_B(Br);
    LOAD_B(1);                 // + B1 x8
    STAGE_A(An, 1);            // + A1 x4   (A0x4, B1x8, A1x4 = 16)
    WAITV(12);                 // A0 landed
    WAITL();
    BAR();

    // ---- main loop: kk = 0 .. NK-3 ----
    for (int kk = 0; kk < NK - 2; kk++) {
        COMPUTE();             // reads Ar/Br (tile kk)
        WAITV(4);              // B(kk+1) landed; A(kk+1) x4 in flight
        WRITE_B(Bw);           // Bs[nxt] <- breg
        LOAD_B(kk + 2);        // + B(kk+2) x8
        STAGE_A(Aw, kk + 2);   // + A(kk+2) x4
        WAITV(12);             // A(kk+1) landed
        WAITL();
        BAR();
        u16* t = Ar; Ar = An; An = Aw; Aw = t;
        t = Br; Br = Bw; Bw = t;
    }
    // ---- iter NK-2 ----
    COMPUTE();
    WAITV(4);                  // B(NK-1) landed
    WRITE_B(Bw);
    WAITV(0);                  // A(NK-1) landed (epilogue of pipeline)
    WAITL();
    BAR();
    { u16* t = Ar; Ar = An; An = Aw; Aw = t; t = Br; Br = Bw; Bw = t; }
    // ---- iter NK-1 ----
    COMPUTE();

#undef LOAD_B
#undef STAGE_A
#undef WRITE_B
#undef COMPUTE
#undef WAITV
#undef WAITL
#undef BAR

    // epilogue (C/D layout: col = lane&15, row = (lane>>4)*4 + j)
    int cb = lane & 15;
    int rq = lane >> 4;
#pragma unroll
    for (int m = 0; m < 4; m++) {
        int rbase = wr * 64 + m * 16 + rq * 4;
#pragma unroll
        for (int n = 0; n < 4; n++) {
            int col = n0 + wc * 64 + n * 16 + cb;
            float bias = biasAll[(size_t)e * NDIM + col];
#pragma unroll
            for (int j = 0; j < 4; j++) {
                int r = rbase + j;
                if (r < nrows) {
                    float v = acc[m][n][j] + bias;
                    int p = row0 + r;
                    if (EPI == 1) {
                        float g = 0.5f * v * (1.0f + erff(v * 0.70710678118654752f));
                        Hout[(size_t)p * NDIM + col] = f2bf(g);
                    } else {
                        int trow = perm[p];
                        Fout[(size_t)trow * NDIM + col] = v;
                    }
                }
            }
        }
    }
}

extern "C" void kernel_launch(void* const* d_in, const int* in_sizes, int n_in,
                              void* d_out, int out_size, void* d_ws, size_t ws_size,
                              hipStream_t stream) {
    const float* x  = (const float*)d_in[0];
    const float* Wg = (const float*)d_in[1];
    const float* W1 = (const float*)d_in[2];
    const float* b1 = (const float*)d_in[3];
    const float* W2 = (const float*)d_in[4];
    const float* b2 = (const float*)d_in[5];
    float* out = (float*)d_out;

    char* ws = (char*)d_ws;
    int* ids    = (int*)(ws + 0);          // 16384 B
    int* counts = (int*)(ws + 16384);      // 32 B
    int* offs   = (int*)(ws + 16448);      // 32 B
    int* cursor = (int*)(ws + 16512);      // 32 B
    int* perm   = (int*)(ws + 16576);      // 16384 B
    u16* Xg     = (u16*)(ws + 33024);      // 8 MiB   (4096x1024 bf16)
    u16* H      = (u16*)(ws + 33024 + 8388608);  // 32 MiB (4096x4096 bf16)

    k_init<<<dim3(1), dim3(64), 0, stream>>>(counts, cursor);
    k_router<<<dim3(NTOK / 4), dim3(256), 0, stream>>>(x, Wg, ids, counts);
    k_scan<<<dim3(1), dim3(64), 0, stream>>>(counts, offs);
    k_gather<<<dim3(NTOK), dim3(256), 0, stream>>>(x, ids, offs, cursor, perm, Xg);
    k_gemm<DIMSZ, HID, 1><<<dim3(RT_MAX * (HID / 128)), dim3(256), 0, stream>>>(
        Xg, W1, b1, counts, offs, perm, H, (float*)nullptr);
    k_gemm<HID, DIMSZ, 2><<<dim3(RT_MAX * (DIMSZ / 128)), dim3(256), 0, stream>>>(
        H, W2, b2, counts, offs, perm, (u16*)nullptr, out);
}